// Round 7
// baseline (599.706 us; speedup 1.0000x reference)
//
#include <hip/hip_runtime.h>
#include <hip/hip_bf16.h>

#define BB 256
#define TT 512
#define EE 300
#define G4 200     // 4*H1
#define BKP 20     // proj stage depth (300 = 15*20)
#define NST 15
#define WSG (BKP * 50)   // float4 granules per stage = 1000

// permuted gate col: G1 column jp corresponds to W row (jp&3)*50 + (jp>>2).

__device__ __forceinline__ float sigm(float x) {
    return __builtin_amdgcn_rcpf(1.f + __builtin_amdgcn_exp2f(-1.442695040888963f * x));
}
__device__ __forceinline__ float tanh_(float x) {
    float t = __builtin_amdgcn_exp2f(2.885390081777927f * x);   // e^(2x)
    return 1.f - 2.f * __builtin_amdgcn_rcpf(t + 1.f);
}

// quad broadcast via DPP: all 4 lanes of a quad get quad-lane C's value
template <int C>
__device__ __forceinline__ float qb(float v) {
    return __int_as_float(__builtin_amdgcn_mov_dpp(__float_as_int(v), C, 0xF, 0xF, true));
}

// ---------------------------------------------------------------------------
// K1: permuted transpose W_ih1 [200,300] -> Wt [300][200] (unpadded, linear)
__global__ void wtrans_kernel(const float* __restrict__ W, float* __restrict__ Wt) {
    int e = blockIdx.x;        // 0..299
    int j = threadIdx.x;       // 0..255
    if (j < G4) {
        int row = (j & 3) * 50 + (j >> 2);
        Wt[e * G4 + j] = W[row * EE + e];
    }
}

// ---------------------------------------------------------------------------
// K2: G1[bb][t][jp] = b1[row(jp)] + emb[x[b][t]] . W_ih1[row(jp)]
// 512 thr, tile 64t x 200j, thread tile 4t x 8j. W double-buffered in LDS via
// global_load_lds (dwordx4); stage arrival via counted vmcnt (never drain).
__device__ __forceinline__ float f4get(const float4& v, int u) {
    return u == 0 ? v.x : u == 1 ? v.y : u == 2 ? v.z : v.w;
}

__device__ __forceinline__ void issue_stage(const float4* __restrict__ Wt4,
                                            int s, float4* dst, int tid) {
    const int wave = tid >> 6;
    const int lane = tid & 63;
    const float4* src = Wt4 + (size_t)s * WSG;
    #pragma unroll
    for (int r = 0; r < 2; ++r) {
        int idx = r * 512 + wave * 64 + lane;    // wave-uniform base + lane
        if (idx < WSG) {
            __builtin_amdgcn_global_load_lds(
                (const __attribute__((address_space(1))) void*)(src + idx),
                (__attribute__((address_space(3))) void*)(dst + idx),
                16, 0, 0);
        }
    }
}

__global__ __launch_bounds__(512) void proj_kernel(
    const int* __restrict__ x, const int* __restrict__ lengths,
    const float* __restrict__ emb, const float* __restrict__ b1,
    const float* __restrict__ Wt, float* __restrict__ G1, int b0)
{
    const int b  = b0 + blockIdx.y;
    const int t0 = blockIdx.x * 64;
    const int len = lengths[b];
    if (t0 >= len) return;                       // uniform: whole tile padding

    const int tid = threadIdx.x;
    const int rg  = tid >> 5;                    // 0..15: rows rg*4 .. rg*4+3
    const int jg  = tid & 31;                    // col group; valid if jg<25
    const bool active = (jg < 25);

    __shared__ float4 Ws4[2][WSG];               // 2 x 16 KB double buffer

    const float* er[4];
    #pragma unroll
    for (int q = 0; q < 4; ++q)
        er[q] = emb + (size_t)x[b * TT + t0 + rg * 4 + q] * EE;

    float acc[4][8];
    {
        float bv[8];
        #pragma unroll
        for (int k = 0; k < 8; ++k) {
            int c = (k < 4) ? (4 * jg + k) : (96 + 4 * jg + k);
            bv[k] = active ? b1[(c & 3) * 50 + (c >> 2)] : 0.f;
        }
        #pragma unroll
        for (int q = 0; q < 4; ++q)
            #pragma unroll
            for (int k = 0; k < 8; ++k) acc[q][k] = bv[k];
    }

    const float4* Wt4 = (const float4*)Wt;       // 300*50 float4, linear

    // prologue: issue stage 0 DMA, then A prefetch (2-deep)
    issue_stage(Wt4, 0, Ws4[0], tid);
    float4 avn[4], avn2[4];
    #pragma unroll
    for (int q = 0; q < 4; ++q) avn[q]  = *(const float4*)(er[q]);
    #pragma unroll
    for (int q = 0; q < 4; ++q) avn2[q] = *(const float4*)(er[q] + 4);

    for (int s = 0; s < NST; ++s) {
        const float4* Wcur = Ws4[s & 1];
        // stage-s DMA (oldest vmem ops) complete; 8 youngest A-loads may fly
        asm volatile("s_waitcnt vmcnt(8)" ::: "memory");
        __builtin_amdgcn_s_barrier();
        __builtin_amdgcn_sched_barrier(0);
        if (s + 1 < NST)
            issue_stage(Wt4, s + 1, Ws4[(s + 1) & 1], tid);

        #pragma unroll
        for (int kk = 0; kk < BKP / 4; ++kk) {
            float4 av[4];
            #pragma unroll
            for (int q = 0; q < 4; ++q) { av[q] = avn[q]; avn[q] = avn2[q]; }
            int en2 = s * BKP + kk * 4 + 8;       // 2 slices ahead
            if (en2 > EE - 4) en2 = EE - 4;
            #pragma unroll
            for (int q = 0; q < 4; ++q)
                avn2[q] = *(const float4*)(er[q] + en2);
            if (active) {
                #pragma unroll
                for (int u = 0; u < 4; ++u) {
                    float4 w0 = Wcur[(kk * 4 + u) * 50 + jg];
                    float4 w1 = Wcur[(kk * 4 + u) * 50 + 25 + jg];
                    #pragma unroll
                    for (int q = 0; q < 4; ++q) {
                        float a = f4get(av[q], u);
                        acc[q][0] = fmaf(a, w0.x, acc[q][0]);
                        acc[q][1] = fmaf(a, w0.y, acc[q][1]);
                        acc[q][2] = fmaf(a, w0.z, acc[q][2]);
                        acc[q][3] = fmaf(a, w0.w, acc[q][3]);
                        acc[q][4] = fmaf(a, w1.x, acc[q][4]);
                        acc[q][5] = fmaf(a, w1.y, acc[q][5]);
                        acc[q][6] = fmaf(a, w1.z, acc[q][6]);
                        acc[q][7] = fmaf(a, w1.w, acc[q][7]);
                    }
                }
            }
        }
    }

    if (active) {
        float* gbase = G1 + ((size_t)blockIdx.y * TT + t0) * G4;
        #pragma unroll
        for (int q = 0; q < 4; ++q) {
            float* gp = gbase + (size_t)(rg * 4 + q) * G4;
            *(float4*)(gp + 4 * jg)       = make_float4(acc[q][0], acc[q][1], acc[q][2], acc[q][3]);
            *(float4*)(gp + 100 + 4 * jg) = make_float4(acc[q][4], acc[q][5], acc[q][6], acc[q][7]);
        }
    }
}

// ---------------------------------------------------------------------------
// K3: recurrence. One block (512 thr = 8 waves) per batch element.
// 8-lane group = one unit: sub=tid&7 -> gate g=sub&3, half=sub>>2.
// Each thread: 28-elem half-dot; halves combined via shfl_xor(4); gates
// broadcast via quad DPP. One barrier/step.
__global__ __launch_bounds__(512, 1) void lstm_kernel(
    const int* __restrict__ lengths,
    const float* __restrict__ W_hh1, const float* __restrict__ W_ih2,
    const float* __restrict__ W_hh2, const float* __restrict__ b2,
    const float* __restrict__ fc1w, const float* __restrict__ fc1b,
    const float* __restrict__ fc2w, const float* __restrict__ fc2b,
    const float* __restrict__ G1, float* __restrict__ out, int b0)
{
    const int bb  = blockIdx.x;
    const int b   = b0 + bb;
    const int tid = threadIdx.x;
    const int len = lengths[b];

    __shared__ __align__(16) float hs[2][72];
    __shared__ __align__(16) float hfin[12];
    __shared__ float zbuf[10];

    if (tid < 72) { hs[0][tid] = 0.f; hs[1][tid] = 0.f; }

    const bool isL1 = (tid < 400);
    const bool isL2 = (tid >= 400 && tid < 480);
    const int  grp  = tid >> 3;
    const int  sub  = tid & 7;
    const int  g    = sub & 3;
    const int  half = sub >> 2;

    float wreg[28];                 // half of W_hh1 row | half of W_ih2 row
    float wregb[12];                // L2 half0: W_hh2 row
    #pragma unroll
    for (int k = 0; k < 28; ++k) wreg[k] = 0.f;
    #pragma unroll
    for (int k = 0; k < 12; ++k) wregb[k] = 0.f;
    float base2 = 0.f;

    if (isL1) {
        int row = g * 50 + grp;
        const float* wp = W_hh1 + row * 50 + half * 28;
        int n = half ? 22 : 28;
        for (int k = 0; k < 28; ++k) wreg[k] = (k < n) ? wp[k] : 0.f;
    } else if (isL2) {
        int u = grp - 50;
        int row = g * 10 + u;
        const float* wp = W_ih2 + row * 50 + half * 28;
        int n = half ? 22 : 28;
        for (int k = 0; k < 28; ++k) wreg[k] = (k < n) ? wp[k] : 0.f;
        if (half == 0) {
            const float* wp2 = W_hh2 + row * 10;
            #pragma unroll
            for (int k = 0; k < 10; ++k) wregb[k] = wp2[k];
            base2 = b2[row];
        }
    }

    const bool gld  = isL1 && (half == 0);        // G1-loading lanes
    const int  gcol = gld ? (4 * grp + g) : 0;    // permuted column jp
    const bool wr   = (sub == 0) && (tid < 480);
    const int  slot = isL1 ? grp : (56 + grp - 50);

    float h1v[28], h2v[12];
    #pragma unroll
    for (int k = 0; k < 28; ++k) h1v[k] = 0.f;
    #pragma unroll
    for (int k = 0; k < 12; ++k) h2v[k] = 0.f;

    float c = 0.f;
    const float* g1p = G1 + (size_t)bb * TT * G4;
    float p0 = 0.f, p1 = 0.f, p2 = 0.f;          // 3-deep G1 prefetch
    if (gld) {
        int t1 = (1 < len) ? 1 : len - 1;
        int t2 = (2 < len) ? 2 : len - 1;
        p0 = g1p[gcol];
        p1 = g1p[(size_t)t1 * G4 + gcol];
        p2 = g1p[(size_t)t2 * G4 + gcol];
    }

    __syncthreads();                              // LDS zero-init visible

    for (int i = 0; i < len; ++i) {
        float base = gld ? p0 : ((isL2 && half == 0) ? base2 : 0.f);
        p0 = p1; p1 = p2;
        if (gld) {
            int tn = (i + 3 < len) ? i + 3 : len - 1;
            p2 = g1p[(size_t)tn * G4 + gcol];      // never drained
        }

        float s0 = 0.f, s1 = 0.f, s2 = 0.f, s3 = 0.f;
        #pragma unroll
        for (int m = 0; m < 7; ++m) {
            s0 = fmaf(wreg[4*m+0], h1v[4*m+0], s0);
            s1 = fmaf(wreg[4*m+1], h1v[4*m+1], s1);
            s2 = fmaf(wreg[4*m+2], h1v[4*m+2], s2);
            s3 = fmaf(wreg[4*m+3], h1v[4*m+3], s3);
        }
        #pragma unroll
        for (int m = 0; m < 3; ++m) {
            s0 = fmaf(wregb[4*m+0], h2v[4*m+0], s0);
            s1 = fmaf(wregb[4*m+1], h2v[4*m+1], s1);
            s2 = fmaf(wregb[4*m+2], h2v[4*m+2], s2);
            s3 = fmaf(wregb[4*m+3], h2v[4*m+3], s3);
        }
        float t = base + (s0 + s1) + (s2 + s3);
        float full = t + __shfl_xor(t, 4, 64);     // combine the two halves

        float gi = qb<0x00>(full);
        float gf = qb<0x55>(full);
        float gg = qb<0xAA>(full);
        float go = qb<0xFF>(full);
        float cn = sigm(gf) * c + sigm(gi) * tanh_(gg);
        float hn = sigm(go) * tanh_(cn);
        if (isL2 && i == 0) { cn = 0.f; hn = 0.f; }   // L2 lag: h2(-1)=0
        c = cn;
        if (wr) hs[i & 1][slot] = hn;

        asm volatile("s_waitcnt lgkmcnt(0)" ::: "memory");
        __builtin_amdgcn_s_barrier();
        __builtin_amdgcn_sched_barrier(0);

        // read own half of h(i) (and h2(i-1) for waves 6-7, wave-uniform guard)
        const float* hb = hs[i & 1] + half * 28;
        #pragma unroll
        for (int m = 0; m < 7; ++m) {
            float4 v = *(const float4*)(hb + 4 * m);
            h1v[4*m+0] = v.x; h1v[4*m+1] = v.y;
            h1v[4*m+2] = v.z; h1v[4*m+3] = v.w;
        }
        if (tid >= 384) {
            const float* hb2 = hs[i & 1] + 56;
            #pragma unroll
            for (int m = 0; m < 3; ++m) {
                float4 v = *(const float4*)(hb2 + 4 * m);
                h2v[4*m+0] = v.x; h2v[4*m+1] = v.y;
                h2v[4*m+2] = v.z; h2v[4*m+3] = v.w;
            }
        }
    }

    // ---- tail: L2 computes h2(len-1) from h1(len-1), h2(len-2)
    {
        float s0 = 0.f, s1 = 0.f, s2 = 0.f, s3 = 0.f;
        #pragma unroll
        for (int m = 0; m < 7; ++m) {
            s0 = fmaf(wreg[4*m+0], h1v[4*m+0], s0);
            s1 = fmaf(wreg[4*m+1], h1v[4*m+1], s1);
            s2 = fmaf(wreg[4*m+2], h1v[4*m+2], s2);
            s3 = fmaf(wreg[4*m+3], h1v[4*m+3], s3);
        }
        #pragma unroll
        for (int m = 0; m < 3; ++m) {
            s0 = fmaf(wregb[4*m+0], h2v[4*m+0], s0);
            s1 = fmaf(wregb[4*m+1], h2v[4*m+1], s1);
            s2 = fmaf(wregb[4*m+2], h2v[4*m+2], s2);
            s3 = fmaf(wregb[4*m+3], h2v[4*m+3], s3);
        }
        float t = ((isL2 && half == 0) ? base2 : 0.f) + (s0 + s1) + (s2 + s3);
        float full = t + __shfl_xor(t, 4, 64);
        float gi = qb<0x00>(full);
        float gf = qb<0x55>(full);
        float gg = qb<0xAA>(full);
        float go = qb<0xFF>(full);
        float cn = sigm(gf) * c + sigm(gi) * tanh_(gg);
        float hn = sigm(go) * tanh_(cn);
        if (isL2 && sub == 0) hfin[grp - 50] = hn;
    }
    __syncthreads();

    // ---- MLP head
    if (tid < 10) {
        float s = fc1b[tid];
        #pragma unroll
        for (int e = 0; e < 10; ++e) s = fmaf(fc1w[tid * 10 + e], hfin[e], s);
        zbuf[tid] = s > 0.f ? s : 0.f;
    }
    __syncthreads();
    if (tid == 0) {
        float s = fc2b[0];
        #pragma unroll
        for (int e = 0; e < 10; ++e) s = fmaf(fc2w[e], zbuf[e], s);
        out[b] = s;
    }
}

// ---------------------------------------------------------------------------
extern "C" void kernel_launch(void* const* d_in, const int* in_sizes, int n_in,
                              void* d_out, int out_size, void* d_ws, size_t ws_size,
                              hipStream_t stream)
{
    const int*   x     = (const int*)  d_in[0];
    const int*   len   = (const int*)  d_in[1];
    const float* emb   = (const float*)d_in[2];
    const float* W_ih1 = (const float*)d_in[3];
    const float* W_hh1 = (const float*)d_in[4];
    const float* b1    = (const float*)d_in[5];
    const float* W_ih2 = (const float*)d_in[6];
    const float* W_hh2 = (const float*)d_in[7];
    const float* b2    = (const float*)d_in[8];
    const float* fc1w  = (const float*)d_in[9];
    const float* fc1b  = (const float*)d_in[10];
    const float* fc2w  = (const float*)d_in[11];
    const float* fc2b  = (const float*)d_in[12];
    float* out = (float*)d_out;

    const size_t wt_bytes = (size_t)EE * G4 * sizeof(float);     // 240000
    const size_t per_b    = (size_t)TT * G4 * sizeof(float);     // 409600
    float* Wt = (float*)d_ws;
    size_t head = (wt_bytes + 255) & ~255ull;
    float* G1 = (float*)((char*)d_ws + head);

    size_t avail = ws_size > head ? ws_size - head : 0;
    int chunk = (int)(avail / per_b);
    if (chunk < 1) chunk = 1;
    if (chunk > BB) chunk = BB;

    wtrans_kernel<<<dim3(EE), dim3(256), 0, stream>>>(W_ih1, Wt);

    for (int b0 = 0; b0 < BB; b0 += chunk) {
        int nb = (BB - b0) < chunk ? (BB - b0) : chunk;
        proj_kernel<<<dim3(TT / 64, nb), dim3(512), 0, stream>>>(
            x, len, emb, b1, Wt, G1, b0);
        lstm_kernel<<<dim3(nb), dim3(512), 0, stream>>>(
            len, W_hh1, W_ih2, W_hh2, b2, fc1w, fc1b, fc2w, fc2b, G1, out, b0);
    }
}

// Round 8
// 537.121 us; speedup vs baseline: 1.1165x; 1.1165x over previous
//
#include <hip/hip_runtime.h>
#include <hip/hip_bf16.h>

#define BB 256
#define TT 512
#define EE 300
#define G4 200     // 4*H1
#define NPAD 208   // padded gate dim
#define KP 1216    // split K': 4*300 padded to 19*64
#define KC 64      // K' per chunk
#define NCH 19
#define NT 13      // N tiles of 16
#define ALP 72     // padded LDS row length (bf16 elems) -> 144B rows

typedef __attribute__((ext_vector_type(8))) short short8v;
typedef __attribute__((ext_vector_type(4))) float float4v;
typedef __attribute__((ext_vector_type(4))) unsigned int uint4v;

// permuted gate col: col jp corresponds to W row (jp&3)*50 + (jp>>2).

__device__ __forceinline__ float sigm(float x) {
    return __builtin_amdgcn_rcpf(1.f + __builtin_amdgcn_exp2f(-1.442695040888963f * x));
}
__device__ __forceinline__ float tanh_(float x) {
    float t = __builtin_amdgcn_exp2f(2.885390081777927f * x);   // e^(2x)
    return 1.f - 2.f * __builtin_amdgcn_rcpf(t + 1.f);
}
template <int C>
__device__ __forceinline__ float qb(float v) {
    return __int_as_float(__builtin_amdgcn_mov_dpp(__float_as_int(v), C, 0xF, 0xF, true));
}

// split a into bf16 hi/lo (round-to-nearest-even): a ~= hi + lo, err ~2^-16 rel
__device__ __forceinline__ uint2 bfsplit(float a) {
    unsigned u = __float_as_uint(a);
    unsigned rh = (u + 0x7FFFu + ((u >> 16) & 1u)) & 0xFFFF0000u;
    float l = a - __uint_as_float(rh);
    unsigned v = __float_as_uint(l);
    unsigned rl = (v + 0x7FFFu + ((v >> 16) & 1u)) >> 16;
    return make_uint2(rh >> 16, rl);
}

// ---------------------------------------------------------------------------
// K1: build split-bf16 B' [NPAD][KP] and permuted bias.
// B'[j][4k+0]=wh, [4k+1]=wh, [4k+2]=wl, [4k+3]=wl  where w = W_ih1[row(j)][k]
__global__ void wtrans_kernel(const float* __restrict__ W, const float* __restrict__ b1,
                              unsigned* __restrict__ Btg, float* __restrict__ b1p) {
    int e = blockIdx.x;        // 0..299
    int j = threadIdx.x;       // 0..255, valid < 208
    if (j >= NPAD) return;
    float w = 0.f;
    if (j < G4) w = W[((j & 3) * 50 + (j >> 2)) * EE + e];
    uint2 s = bfsplit(w);
    unsigned dw0 = s.x | (s.x << 16);
    unsigned dw1 = s.y | (s.y << 16);
    *(uint2*)(Btg + (size_t)j * (KP / 2) + 2 * e) = make_uint2(dw0, dw1);
    if (e == 0) b1p[j] = (j < G4) ? b1[(j & 3) * 50 + (j >> 2)] : 0.f;
}

// ---------------------------------------------------------------------------
// K2: MFMA proj. 128 thr = 2 waves. Block tile M=64 (wave: 2 Mtiles of 16),
// N=208 (13 tiles), K'=1216 in 19 chunks of 64. A built on the fly
// (gather + split, A'=(ah,al,ah,al)), B staged from precomputed Btg.
__global__ __launch_bounds__(128) void proj_kernel(
    const int* __restrict__ x, const int* __restrict__ lengths,
    const float* __restrict__ emb, const unsigned* __restrict__ Btg,
    const float* __restrict__ b1p, float* __restrict__ G1, int b0)
{
    const int b  = b0 + blockIdx.y;
    const int t0 = blockIdx.x * 64;
    const int len = lengths[b];
    if (t0 >= len) return;                       // uniform: whole tile padding

    const int tid  = threadIdx.x;
    const int wv   = tid >> 6;
    const int lane = tid & 63;

    __shared__ unsigned short AL[64 * ALP];      // 9216 B
    __shared__ unsigned short BL[NPAD * ALP];    // 29952 B

    // fixed per-thread A task geometry: rows (tid>>2) and +32, k-group tid&3
    const int arow = tid >> 2;                   // 0..31
    const int ag   = tid & 3;
    const float* erA0 = emb + (size_t)x[b * TT + t0 + arow] * EE;
    const float* erA1 = emb + (size_t)x[b * TT + t0 + arow + 32] * EE;
    // fixed B task geometry: seg tid&7, rows (tid>>3) + 16*i
    const int bseg  = tid & 7;
    const int brow0 = tid >> 3;

    float4v acc[2][NT] = {};

    for (int c = 0; c < NCH; ++c) {
        __syncthreads();                         // prev chunk's LDS reads done
        // ---- stage B chunk: rows brow0+16i, 16B seg each
        {
            const unsigned* bsrc = Btg + c * (KC / 2) + bseg * 4;
            #pragma unroll
            for (int i = 0; i < 13; ++i) {
                int row = brow0 + 16 * i;
                uint4v d = *(const uint4v*)(bsrc + (size_t)row * (KP / 2));
                *(uint4v*)((unsigned*)&BL[row * ALP + bseg * 8]) = d;
            }
        }
        // ---- stage A chunk: 2 rows, 4 orig-k each -> 16 K' bf16 (32B)
        {
            int k0 = c * 16 + ag * 4;
            #pragma unroll
            for (int i = 0; i < 2; ++i) {
                const float* er = i ? erA1 : erA0;
                int row = arow + 32 * i;
                float a0 = 0.f, a1 = 0.f, a2 = 0.f, a3 = 0.f;
                if (k0 + 3 < EE) {
                    float4 v = *(const float4*)(er + k0);
                    a0 = v.x; a1 = v.y; a2 = v.z; a3 = v.w;
                } else {
                    if (k0     < EE) a0 = er[k0];
                    if (k0 + 1 < EE) a1 = er[k0 + 1];
                    if (k0 + 2 < EE) a2 = er[k0 + 2];
                    if (k0 + 3 < EE) a3 = er[k0 + 3];
                }
                uint2 s0 = bfsplit(a0), s1 = bfsplit(a1);
                uint2 s2 = bfsplit(a2), s3 = bfsplit(a3);
                unsigned p0 = s0.x | (s0.y << 16), p1 = s1.x | (s1.y << 16);
                unsigned p2 = s2.x | (s2.y << 16), p3 = s3.x | (s3.y << 16);
                unsigned* dst = (unsigned*)&AL[row * ALP + ag * 16];
                *(uint4v*)(dst)     = uint4v{p0, p0, p1, p1};
                *(uint4v*)(dst + 4) = uint4v{p2, p2, p3, p3};
            }
        }
        __syncthreads();                         // staged data visible
        // ---- compute: 2 K-subs x (2 Mtiles x 13 Ntiles)
        #pragma unroll
        for (int s = 0; s < 2; ++s) {
            const int ko = s * 32 + (lane >> 4) * 8;
            short8v aF0 = *(const short8v*)&AL[(wv * 32 +      (lane & 15)) * ALP + ko];
            short8v aF1 = *(const short8v*)&AL[(wv * 32 + 16 + (lane & 15)) * ALP + ko];
            #pragma unroll
            for (int nt = 0; nt < NT; ++nt) {
                short8v bF = *(const short8v*)&BL[(nt * 16 + (lane & 15)) * ALP + ko];
                acc[0][nt] = __builtin_amdgcn_mfma_f32_16x16x32_bf16(aF0, bF, acc[0][nt], 0, 0, 0);
                acc[1][nt] = __builtin_amdgcn_mfma_f32_16x16x32_bf16(aF1, bF, acc[1][nt], 0, 0, 0);
            }
        }
    }

    // ---- epilogue: C frag col=lane&15, row=(lane>>4)*4+r  [m89]
    float* gbase = G1 + ((size_t)blockIdx.y * TT + t0) * G4;
    const int col = lane & 15, rq = lane >> 4;
    #pragma unroll
    for (int nt = 0; nt < NT; ++nt) {
        int jp = nt * 16 + col;
        if (jp < G4) {
            float bias = b1p[jp];
            #pragma unroll
            for (int mt = 0; mt < 2; ++mt) {
                int trow = wv * 32 + mt * 16 + rq * 4;
                #pragma unroll
                for (int r = 0; r < 4; ++r)
                    gbase[(size_t)(trow + r) * G4 + jp] = acc[mt][nt][r] + bias;
            }
        }
    }
}

// ---------------------------------------------------------------------------
// K3: recurrence (unchanged from R6's working version). 512 thr = 8 waves.
__global__ __launch_bounds__(512, 1) void lstm_kernel(
    const int* __restrict__ lengths,
    const float* __restrict__ W_hh1, const float* __restrict__ W_ih2,
    const float* __restrict__ W_hh2, const float* __restrict__ b2,
    const float* __restrict__ fc1w, const float* __restrict__ fc1b,
    const float* __restrict__ fc2w, const float* __restrict__ fc2b,
    const float* __restrict__ G1, float* __restrict__ out, int b0)
{
    const int bb  = blockIdx.x;
    const int b   = b0 + bb;
    const int tid = threadIdx.x;
    const int len = lengths[b];

    __shared__ __align__(16) float hs[2][72];
    __shared__ __align__(16) float hfin[12];
    __shared__ float zbuf[10];

    if (tid < 72) { hs[0][tid] = 0.f; hs[1][tid] = 0.f; }

    const bool isL1 = (tid < 400);
    const bool isL2 = (tid >= 400 && tid < 480);
    const int  grp  = tid >> 3;
    const int  sub  = tid & 7;
    const int  g    = sub & 3;
    const int  half = sub >> 2;

    float wreg[28];
    float wregb[12];
    #pragma unroll
    for (int k = 0; k < 28; ++k) wreg[k] = 0.f;
    #pragma unroll
    for (int k = 0; k < 12; ++k) wregb[k] = 0.f;
    float base2 = 0.f;

    if (isL1) {
        int row = g * 50 + grp;
        const float* wp = W_hh1 + row * 50 + half * 28;
        int n = half ? 22 : 28;
        for (int k = 0; k < 28; ++k) wreg[k] = (k < n) ? wp[k] : 0.f;
    } else if (isL2) {
        int u = grp - 50;
        int row = g * 10 + u;
        const float* wp = W_ih2 + row * 50 + half * 28;
        int n = half ? 22 : 28;
        for (int k = 0; k < 28; ++k) wreg[k] = (k < n) ? wp[k] : 0.f;
        if (half == 0) {
            const float* wp2 = W_hh2 + row * 10;
            #pragma unroll
            for (int k = 0; k < 10; ++k) wregb[k] = wp2[k];
            base2 = b2[row];
        }
    }

    const bool gld  = isL1 && (half == 0);
    const int  gcol = gld ? (4 * grp + g) : 0;
    const bool wr   = (sub == 0) && (tid < 480);
    const int  slot = isL1 ? grp : (56 + grp - 50);

    float h1v[28], h2v[12];
    #pragma unroll
    for (int k = 0; k < 28; ++k) h1v[k] = 0.f;
    #pragma unroll
    for (int k = 0; k < 12; ++k) h2v[k] = 0.f;

    float c = 0.f;
    const float* g1p = G1 + (size_t)bb * TT * G4;
    float p0 = 0.f, p1 = 0.f, p2 = 0.f;
    if (gld) {
        int t1 = (1 < len) ? 1 : len - 1;
        int t2 = (2 < len) ? 2 : len - 1;
        p0 = g1p[gcol];
        p1 = g1p[(size_t)t1 * G4 + gcol];
        p2 = g1p[(size_t)t2 * G4 + gcol];
    }

    __syncthreads();

    for (int i = 0; i < len; ++i) {
        float base = gld ? p0 : ((isL2 && half == 0) ? base2 : 0.f);
        p0 = p1; p1 = p2;
        if (gld) {
            int tn = (i + 3 < len) ? i + 3 : len - 1;
            p2 = g1p[(size_t)tn * G4 + gcol];
        }

        float s0 = 0.f, s1 = 0.f, s2 = 0.f, s3 = 0.f;
        #pragma unroll
        for (int m = 0; m < 7; ++m) {
            s0 = fmaf(wreg[4*m+0], h1v[4*m+0], s0);
            s1 = fmaf(wreg[4*m+1], h1v[4*m+1], s1);
            s2 = fmaf(wreg[4*m+2], h1v[4*m+2], s2);
            s3 = fmaf(wreg[4*m+3], h1v[4*m+3], s3);
        }
        #pragma unroll
        for (int m = 0; m < 3; ++m) {
            s0 = fmaf(wregb[4*m+0], h2v[4*m+0], s0);
            s1 = fmaf(wregb[4*m+1], h2v[4*m+1], s1);
            s2 = fmaf(wregb[4*m+2], h2v[4*m+2], s2);
            s3 = fmaf(wregb[4*m+3], h2v[4*m+3], s3);
        }
        float t = base + (s0 + s1) + (s2 + s3);
        float full = t + __shfl_xor(t, 4, 64);

        float gi = qb<0x00>(full);
        float gf = qb<0x55>(full);
        float gg = qb<0xAA>(full);
        float go = qb<0xFF>(full);
        float cn = sigm(gf) * c + sigm(gi) * tanh_(gg);
        float hn = sigm(go) * tanh_(cn);
        if (isL2 && i == 0) { cn = 0.f; hn = 0.f; }
        c = cn;
        if (wr) hs[i & 1][slot] = hn;

        asm volatile("s_waitcnt lgkmcnt(0)" ::: "memory");
        __builtin_amdgcn_s_barrier();
        __builtin_amdgcn_sched_barrier(0);

        const float* hb = hs[i & 1] + half * 28;
        #pragma unroll
        for (int m = 0; m < 7; ++m) {
            float4 v = *(const float4*)(hb + 4 * m);
            h1v[4*m+0] = v.x; h1v[4*m+1] = v.y;
            h1v[4*m+2] = v.z; h1v[4*m+3] = v.w;
        }
        if (tid >= 384) {
            const float* hb2 = hs[i & 1] + 56;
            #pragma unroll
            for (int m = 0; m < 3; ++m) {
                float4 v = *(const float4*)(hb2 + 4 * m);
                h2v[4*m+0] = v.x; h2v[4*m+1] = v.y;
                h2v[4*m+2] = v.z; h2v[4*m+3] = v.w;
            }
        }
    }

    {
        float s0 = 0.f, s1 = 0.f, s2 = 0.f, s3 = 0.f;
        #pragma unroll
        for (int m = 0; m < 7; ++m) {
            s0 = fmaf(wreg[4*m+0], h1v[4*m+0], s0);
            s1 = fmaf(wreg[4*m+1], h1v[4*m+1], s1);
            s2 = fmaf(wreg[4*m+2], h1v[4*m+2], s2);
            s3 = fmaf(wreg[4*m+3], h1v[4*m+3], s3);
        }
        #pragma unroll
        for (int m = 0; m < 3; ++m) {
            s0 = fmaf(wregb[4*m+0], h2v[4*m+0], s0);
            s1 = fmaf(wregb[4*m+1], h2v[4*m+1], s1);
            s2 = fmaf(wregb[4*m+2], h2v[4*m+2], s2);
            s3 = fmaf(wregb[4*m+3], h2v[4*m+3], s3);
        }
        float t = ((isL2 && half == 0) ? base2 : 0.f) + (s0 + s1) + (s2 + s3);
        float full = t + __shfl_xor(t, 4, 64);
        float gi = qb<0x00>(full);
        float gf = qb<0x55>(full);
        float gg = qb<0xAA>(full);
        float go = qb<0xFF>(full);
        float cn = sigm(gf) * c + sigm(gi) * tanh_(gg);
        float hn = sigm(go) * tanh_(cn);
        if (isL2 && sub == 0) hfin[grp - 50] = hn;
    }
    __syncthreads();

    if (tid < 10) {
        float s = fc1b[tid];
        #pragma unroll
        for (int e = 0; e < 10; ++e) s = fmaf(fc1w[tid * 10 + e], hfin[e], s);
        zbuf[tid] = s > 0.f ? s : 0.f;
    }
    __syncthreads();
    if (tid == 0) {
        float s = fc2b[0];
        #pragma unroll
        for (int e = 0; e < 10; ++e) s = fmaf(fc2w[e], zbuf[e], s);
        out[b] = s;
    }
}

// ---------------------------------------------------------------------------
extern "C" void kernel_launch(void* const* d_in, const int* in_sizes, int n_in,
                              void* d_out, int out_size, void* d_ws, size_t ws_size,
                              hipStream_t stream)
{
    const int*   x     = (const int*)  d_in[0];
    const int*   len   = (const int*)  d_in[1];
    const float* emb   = (const float*)d_in[2];
    const float* W_ih1 = (const float*)d_in[3];
    const float* W_hh1 = (const float*)d_in[4];
    const float* b1    = (const float*)d_in[5];
    const float* W_ih2 = (const float*)d_in[6];
    const float* W_hh2 = (const float*)d_in[7];
    const float* b2    = (const float*)d_in[8];
    const float* fc1w  = (const float*)d_in[9];
    const float* fc1b  = (const float*)d_in[10];
    const float* fc2w  = (const float*)d_in[11];
    const float* fc2b  = (const float*)d_in[12];
    float* out = (float*)d_out;

    const size_t btg_bytes = (size_t)NPAD * (KP / 2) * sizeof(unsigned);  // 505856
    const size_t b1p_off   = btg_bytes;                                   // 256-mult
    const size_t head      = (b1p_off + NPAD * sizeof(float) + 255) & ~255ull;
    const size_t per_b     = (size_t)TT * G4 * sizeof(float);             // 409600

    unsigned* Btg = (unsigned*)d_ws;
    float*    b1p = (float*)((char*)d_ws + b1p_off);
    float*    G1  = (float*)((char*)d_ws + head);

    size_t avail = ws_size > head ? ws_size - head : 0;
    int chunk = (int)(avail / per_b);
    if (chunk < 1) chunk = 1;
    if (chunk > BB) chunk = BB;

    wtrans_kernel<<<dim3(EE), dim3(256), 0, stream>>>(W_ih1, b1, Btg, b1p);

    for (int b0 = 0; b0 < BB; b0 += chunk) {
        int nb = (BB - b0) < chunk ? (BB - b0) : chunk;
        proj_kernel<<<dim3(TT / 64, nb), dim3(128), 0, stream>>>(
            x, len, emb, Btg, b1p, G1, b0);
        lstm_kernel<<<dim3(nb), dim3(512), 0, stream>>>(
            len, W_hh1, W_ih2, W_hh2, b2, fc1w, fc1b, fc2w, fc2b, G1, out, b0);
    }
}

// Round 9
// 318.144 us; speedup vs baseline: 1.8850x; 1.6883x over previous
//
#include <hip/hip_runtime.h>
#include <hip/hip_bf16.h>

#define BB 256
#define TT 512
#define EE 300
#define G4 200     // 4*H1
#define NPAD 208   // padded gate dim (13*16)
#define KP 1216    // split K': 4*300 padded to 19*64
#define KC 64      // K' per chunk
#define KPD (KP/2) // 608 dwords per Btg row
#define KCD (KC/2) // 32 dwords per chunk
#define NCH 19
#define NT 13      // N tiles of 16
#define BOFF 8192  // B region byte offset inside a buffer (A: 64*128 = 8192B)
#define BUFB 34816 // bytes per buffer: A 8192 + B 208*128 = 26624

typedef __attribute__((ext_vector_type(8))) short short8v;
typedef __attribute__((ext_vector_type(4))) float float4v;
typedef __attribute__((ext_vector_type(4))) unsigned int uint4v;

// permuted gate col: col jp corresponds to W row (jp&3)*50 + (jp>>2).

__device__ __forceinline__ float sigm(float x) {
    return __builtin_amdgcn_rcpf(1.f + __builtin_amdgcn_exp2f(-1.442695040888963f * x));
}
__device__ __forceinline__ float tanh_(float x) {
    float t = __builtin_amdgcn_exp2f(2.885390081777927f * x);   // e^(2x)
    return 1.f - 2.f * __builtin_amdgcn_rcpf(t + 1.f);
}
template <int C>
__device__ __forceinline__ float qb(float v) {
    return __int_as_float(__builtin_amdgcn_mov_dpp(__float_as_int(v), C, 0xF, 0xF, true));
}

// split a into bf16 hi/lo (RNE): a ~= hi + lo, err ~2^-16 rel
__device__ __forceinline__ uint2 bfsplit(float a) {
    unsigned u = __float_as_uint(a);
    unsigned rh = (u + 0x7FFFu + ((u >> 16) & 1u)) & 0xFFFF0000u;
    float l = a - __uint_as_float(rh);
    unsigned v = __float_as_uint(l);
    unsigned rl = (v + 0x7FFFu + ((v >> 16) & 1u)) >> 16;
    return make_uint2(rh >> 16, rl);
}

// ---------------------------------------------------------------------------
// K1: build split-bf16 B' [NPAD][KP] (row-major) and permuted bias.
// B'[j][4k+0]=wh, [4k+1]=wh, [4k+2]=wl, [4k+3]=wl  where w = W_ih1[row(j)][k]
__global__ void wtrans_kernel(const float* __restrict__ W, const float* __restrict__ b1,
                              unsigned* __restrict__ Btg, float* __restrict__ b1p) {
    int e = blockIdx.x;        // 0..299
    int j = threadIdx.x;       // 0..255, valid < 208
    if (j >= NPAD) return;
    float w = 0.f;
    if (j < G4) w = W[((j & 3) * 50 + (j >> 2)) * EE + e];
    uint2 s = bfsplit(w);
    unsigned dw0 = s.x | (s.x << 16);
    unsigned dw1 = s.y | (s.y << 16);
    *(uint2*)(Btg + (size_t)j * KPD + 2 * e) = make_uint2(dw0, dw1);
    if (e == 0) b1p[j] = (j < G4) ? b1[(j & 3) * 50 + (j >> 2)] : 0.f;
}

// ---------------------------------------------------------------------------
// K2: MFMA proj, 256 thr = 4 waves; block tile M=64 (wave = 1 Mtile of 16),
// N=208 (13 NT), K'=1216 in 19 chunks of 64. Double-buffered LDS; B staged
// by global_load_lds from inverse-swizzled global addresses (linear LDS dst);
// A gathered+split on the fly, ds_write with swizzled dst. LDS rows 128B with
// byte ^= ((row&7)<<4) -> uniform 8 lanes/slot on every b128 read (minimum).
__global__ __launch_bounds__(256, 2) void proj_kernel(
    const int* __restrict__ x, const int* __restrict__ lengths,
    const float* __restrict__ emb, const unsigned* __restrict__ Btg,
    const float* __restrict__ b1p, float* __restrict__ G1, int b0)
{
    const int b  = b0 + blockIdx.y;
    const int t0 = blockIdx.x * 64;
    const int len = lengths[b];
    if (t0 >= len) return;                       // uniform: whole tile padding

    const int tid  = threadIdx.x;
    const int wv   = tid >> 6;
    const int lane = tid & 63;

    __shared__ __align__(16) char lds[2 * BUFB];

    // A task geometry: one row per 4 threads: arow 0..63, quad ag 0..3
    const int arow = tid >> 2;
    const int ag   = tid & 3;
    const float* er = emb + (size_t)x[b * TT + t0 + arow] * EE;

    float4v acc[NT] = {};

    // ---- helpers (inline lambdas) -----------------------------------------
    auto stageB = [&](int c, int q) {
        char* base = lds + q * BUFB + BOFF;      // linear DMA dest region
        #pragma unroll
        for (int rr = 0; rr < 7; ++rr) {
            if (rr < 6 || tid < 128) {           // 1664 granules; tail wave-uniform
                int g   = rr * 256 + tid;
                int row = g >> 3, sl = g & 7;
                const unsigned* src = Btg + (size_t)row * KPD + c * KCD
                                      + ((sl ^ (row & 7)) << 2);   // inverse swizzle
                char* dst = base + (rr * 256 + (tid & ~63)) * 16;  // wave-uniform
                __builtin_amdgcn_global_load_lds(
                    (const __attribute__((address_space(1))) void*)src,
                    (__attribute__((address_space(3))) void*)dst, 16, 0, 0);
            }
        }
    };
    auto loadA = [&](int cc) -> float4 {
        int k0 = cc * 16 + ag * 4;               // orig-k quad (EE mult of 4)
        if (k0 < EE) return *(const float4*)(er + k0);
        return make_float4(0.f, 0.f, 0.f, 0.f);
    };
    auto writeA = [&](int q, float4 av) {
        uint2 s0 = bfsplit(av.x), s1 = bfsplit(av.y);
        uint2 s2 = bfsplit(av.z), s3 = bfsplit(av.w);
        unsigned p0 = s0.x | (s0.y << 16), p1 = s1.x | (s1.y << 16);
        unsigned p2 = s2.x | (s2.y << 16), p3 = s3.x | (s3.y << 16);
        char* base = lds + q * BUFB + (arow << 7);
        int r7 = arow & 7;
        *(uint4v*)(base + ((( 2 * ag    ) ^ r7) << 4)) = uint4v{p0, p0, p1, p1};
        *(uint4v*)(base + (((2 * ag + 1) ^ r7) << 4)) = uint4v{p2, p2, p3, p3};
    };

    // ---- prologue: stage chunk 0 into buf 0 -------------------------------
    stageB(0, 0);
    float4 aval = loadA(0);
    asm volatile("s_waitcnt vmcnt(0)" ::: "memory");
    writeA(0, aval);
    asm volatile("s_waitcnt lgkmcnt(0)" ::: "memory");
    __builtin_amdgcn_s_barrier();
    __builtin_amdgcn_sched_barrier(0);

    int p = 0;
    for (int c = 0; c < NCH; ++c) {
        const int q = p ^ 1;
        if (c + 1 < NCH) {                       // issue next-chunk staging early
            stageB(c + 1, q);
            aval = loadA(c + 1);
        }
        // ---- compute chunk c from buf p
        const int r  = lane & 15;
        const int h  = lane >> 4;
        #pragma unroll
        for (int s = 0; s < 2; ++s) {
            const int sw4 = (((4 * s + h) ^ (r & 7)) << 4);   // swizzled 16B slot
            short8v aF = *(const short8v*)(lds + p * BUFB + ((wv * 16 + r) << 7) + sw4);
            #pragma unroll
            for (int nt = 0; nt < NT; ++nt) {
                short8v bF = *(const short8v*)(lds + p * BUFB + BOFF
                                               + ((nt * 16 + r) << 7) + sw4);
                acc[nt] = __builtin_amdgcn_mfma_f32_16x16x32_bf16(aF, bF, acc[nt], 0, 0, 0);
            }
        }
        if (c + 1 < NCH) {
            asm volatile("s_waitcnt vmcnt(0)" ::: "memory");   // A + B-DMA arrived
            writeA(q, aval);
            asm volatile("s_waitcnt lgkmcnt(0)" ::: "memory");
            __builtin_amdgcn_s_barrier();
            __builtin_amdgcn_sched_barrier(0);
        }
        p = q;
    }

    // ---- epilogue: C frag col=lane&15, row=(lane>>4)*4+r  [m89]
    float* gbase = G1 + ((size_t)blockIdx.y * TT + t0) * G4;
    const int col = lane & 15, rq = lane >> 4;
    #pragma unroll
    for (int nt = 0; nt < NT; ++nt) {
        int jp = nt * 16 + col;
        if (jp < G4) {
            float bias = b1p[jp];
            #pragma unroll
            for (int rr = 0; rr < 4; ++rr)
                gbase[(size_t)(wv * 16 + rq * 4 + rr) * G4 + jp] = acc[nt][rr] + bias;
        }
    }
}

// ---------------------------------------------------------------------------
// K3: recurrence (unchanged). 512 thr = 8 waves, one block per batch element.
__global__ __launch_bounds__(512, 1) void lstm_kernel(
    const int* __restrict__ lengths,
    const float* __restrict__ W_hh1, const float* __restrict__ W_ih2,
    const float* __restrict__ W_hh2, const float* __restrict__ b2,
    const float* __restrict__ fc1w, const float* __restrict__ fc1b,
    const float* __restrict__ fc2w, const float* __restrict__ fc2b,
    const float* __restrict__ G1, float* __restrict__ out, int b0)
{
    const int bb  = blockIdx.x;
    const int b   = b0 + bb;
    const int tid = threadIdx.x;
    const int len = lengths[b];

    __shared__ __align__(16) float hs[2][72];
    __shared__ __align__(16) float hfin[12];
    __shared__ float zbuf[10];

    if (tid < 72) { hs[0][tid] = 0.f; hs[1][tid] = 0.f; }

    const bool isL1 = (tid < 400);
    const bool isL2 = (tid >= 400 && tid < 480);
    const int  grp  = tid >> 3;
    const int  sub  = tid & 7;
    const int  g    = sub & 3;
    const int  half = sub >> 2;

    float wreg[28];
    float wregb[12];
    #pragma unroll
    for (int k = 0; k < 28; ++k) wreg[k] = 0.f;
    #pragma unroll
    for (int k = 0; k < 12; ++k) wregb[k] = 0.f;
    float base2 = 0.f;

    if (isL1) {
        int row = g * 50 + grp;
        const float* wp = W_hh1 + row * 50 + half * 28;
        int n = half ? 22 : 28;
        for (int k = 0; k < 28; ++k) wreg[k] = (k < n) ? wp[k] : 0.f;
    } else if (isL2) {
        int u = grp - 50;
        int row = g * 10 + u;
        const float* wp = W_ih2 + row * 50 + half * 28;
        int n = half ? 22 : 28;
        for (int k = 0; k < 28; ++k) wreg[k] = (k < n) ? wp[k] : 0.f;
        if (half == 0) {
            const float* wp2 = W_hh2 + row * 10;
            #pragma unroll
            for (int k = 0; k < 10; ++k) wregb[k] = wp2[k];
            base2 = b2[row];
        }
    }

    const bool gld  = isL1 && (half == 0);
    const int  gcol = gld ? (4 * grp + g) : 0;
    const bool wr   = (sub == 0) && (tid < 480);
    const int  slot = isL1 ? grp : (56 + grp - 50);

    float h1v[28], h2v[12];
    #pragma unroll
    for (int k = 0; k < 28; ++k) h1v[k] = 0.f;
    #pragma unroll
    for (int k = 0; k < 12; ++k) h2v[k] = 0.f;

    float c = 0.f;
    const float* g1p = G1 + (size_t)bb * TT * G4;
    float p0 = 0.f, p1 = 0.f, p2 = 0.f;
    if (gld) {
        int t1 = (1 < len) ? 1 : len - 1;
        int t2 = (2 < len) ? 2 : len - 1;
        p0 = g1p[gcol];
        p1 = g1p[(size_t)t1 * G4 + gcol];
        p2 = g1p[(size_t)t2 * G4 + gcol];
    }

    __syncthreads();

    for (int i = 0; i < len; ++i) {
        float base = gld ? p0 : ((isL2 && half == 0) ? base2 : 0.f);
        p0 = p1; p1 = p2;
        if (gld) {
            int tn = (i + 3 < len) ? i + 3 : len - 1;
            p2 = g1p[(size_t)tn * G4 + gcol];
        }

        float s0 = 0.f, s1 = 0.f, s2 = 0.f, s3 = 0.f;
        #pragma unroll
        for (int m = 0; m < 7; ++m) {
            s0 = fmaf(wreg[4*m+0], h1v[4*m+0], s0);
            s1 = fmaf(wreg[4*m+1], h1v[4*m+1], s1);
            s2 = fmaf(wreg[4*m+2], h1v[4*m+2], s2);
            s3 = fmaf(wreg[4*m+3], h1v[4*m+3], s3);
        }
        #pragma unroll
        for (int m = 0; m < 3; ++m) {
            s0 = fmaf(wregb[4*m+0], h2v[4*m+0], s0);
            s1 = fmaf(wregb[4*m+1], h2v[4*m+1], s1);
            s2 = fmaf(wregb[4*m+2], h2v[4*m+2], s2);
            s3 = fmaf(wregb[4*m+3], h2v[4*m+3], s3);
        }
        float t = base + (s0 + s1) + (s2 + s3);
        float full = t + __shfl_xor(t, 4, 64);

        float gi = qb<0x00>(full);
        float gf = qb<0x55>(full);
        float gg = qb<0xAA>(full);
        float go = qb<0xFF>(full);
        float cn = sigm(gf) * c + sigm(gi) * tanh_(gg);
        float hn = sigm(go) * tanh_(cn);
        if (isL2 && i == 0) { cn = 0.f; hn = 0.f; }
        c = cn;
        if (wr) hs[i & 1][slot] = hn;

        asm volatile("s_waitcnt lgkmcnt(0)" ::: "memory");
        __builtin_amdgcn_s_barrier();
        __builtin_amdgcn_sched_barrier(0);

        const float* hb = hs[i & 1] + half * 28;
        #pragma unroll
        for (int m = 0; m < 7; ++m) {
            float4 v = *(const float4*)(hb + 4 * m);
            h1v[4*m+0] = v.x; h1v[4*m+1] = v.y;
            h1v[4*m+2] = v.z; h1v[4*m+3] = v.w;
        }
        if (tid >= 384) {
            const float* hb2 = hs[i & 1] + 56;
            #pragma unroll
            for (int m = 0; m < 3; ++m) {
                float4 v = *(const float4*)(hb2 + 4 * m);
                h2v[4*m+0] = v.x; h2v[4*m+1] = v.y;
                h2v[4*m+2] = v.z; h2v[4*m+3] = v.w;
            }
        }
    }

    {
        float s0 = 0.f, s1 = 0.f, s2 = 0.f, s3 = 0.f;
        #pragma unroll
        for (int m = 0; m < 7; ++m) {
            s0 = fmaf(wreg[4*m+0], h1v[4*m+0], s0);
            s1 = fmaf(wreg[4*m+1], h1v[4*m+1], s1);
            s2 = fmaf(wreg[4*m+2], h1v[4*m+2], s2);
            s3 = fmaf(wreg[4*m+3], h1v[4*m+3], s3);
        }
        #pragma unroll
        for (int m = 0; m < 3; ++m) {
            s0 = fmaf(wregb[4*m+0], h2v[4*m+0], s0);
            s1 = fmaf(wregb[4*m+1], h2v[4*m+1], s1);
            s2 = fmaf(wregb[4*m+2], h2v[4*m+2], s2);
            s3 = fmaf(wregb[4*m+3], h2v[4*m+3], s3);
        }
        float t = ((isL2 && half == 0) ? base2 : 0.f) + (s0 + s1) + (s2 + s3);
        float full = t + __shfl_xor(t, 4, 64);
        float gi = qb<0x00>(full);
        float gf = qb<0x55>(full);
        float gg = qb<0xAA>(full);
        float go = qb<0xFF>(full);
        float cn = sigm(gf) * c + sigm(gi) * tanh_(gg);
        float hn = sigm(go) * tanh_(cn);
        if (isL2 && sub == 0) hfin[grp - 50] = hn;
    }
    __syncthreads();

    if (tid < 10) {
        float s = fc1b[tid];
        #pragma unroll
        for (int e = 0; e < 10; ++e) s = fmaf(fc1w[tid * 10 + e], hfin[e], s);
        zbuf[tid] = s > 0.f ? s : 0.f;
    }
    __syncthreads();
    if (tid == 0) {
        float s = fc2b[0];
        #pragma unroll
        for (int e = 0; e < 10; ++e) s = fmaf(fc2w[e], zbuf[e], s);
        out[b] = s;
    }
}

// ---------------------------------------------------------------------------
extern "C" void kernel_launch(void* const* d_in, const int* in_sizes, int n_in,
                              void* d_out, int out_size, void* d_ws, size_t ws_size,
                              hipStream_t stream)
{
    const int*   x     = (const int*)  d_in[0];
    const int*   len   = (const int*)  d_in[1];
    const float* emb   = (const float*)d_in[2];
    const float* W_ih1 = (const float*)d_in[3];
    const float* W_hh1 = (const float*)d_in[4];
    const float* b1    = (const float*)d_in[5];
    const float* W_ih2 = (const float*)d_in[6];
    const float* W_hh2 = (const float*)d_in[7];
    const float* b2    = (const float*)d_in[8];
    const float* fc1w  = (const float*)d_in[9];
    const float* fc1b  = (const float*)d_in[10];
    const float* fc2w  = (const float*)d_in[11];
    const float* fc2b  = (const float*)d_in[12];
    float* out = (float*)d_out;

    const size_t btg_bytes = (size_t)NPAD * KPD * sizeof(unsigned);  // 505856
    const size_t b1p_off   = btg_bytes;
    const size_t head      = (b1p_off + NPAD * sizeof(float) + 255) & ~255ull;
    const size_t per_b     = (size_t)TT * G4 * sizeof(float);        // 409600

    unsigned* Btg = (unsigned*)d_ws;
    float*    b1p = (float*)((char*)d_ws + b1p_off);
    float*    G1  = (float*)((char*)d_ws + head);

    size_t avail = ws_size > head ? ws_size - head : 0;
    int chunk = (int)(avail / per_b);
    if (chunk < 1) chunk = 1;
    if (chunk > BB) chunk = BB;

    wtrans_kernel<<<dim3(EE), dim3(256), 0, stream>>>(W_ih1, b1, Btg, b1p);

    for (int b0 = 0; b0 < BB; b0 += chunk) {
        int nb = (BB - b0) < chunk ? (BB - b0) : chunk;
        proj_kernel<<<dim3(TT / 64, nb), dim3(256), 0, stream>>>(
            x, len, emb, Btg, b1p, G1, b0);
        lstm_kernel<<<dim3(nb), dim3(512), 0, stream>>>(
            len, W_hh1, W_ih2, W_hh2, b2, fc1w, fc1b, fc2w, fc2b, G1, out, b0);
    }
}